// Round 5
// baseline (544.033 us; speedup 1.0000x reference)
//
#include <hip/hip_runtime.h>
#include <hip/hip_bf16.h>
#include <cstdio>

typedef __hip_bfloat16 bf16;
typedef __attribute__((ext_vector_type(8))) short s8v;   // 8 x bf16 (4 VGPRs)
typedef __attribute__((ext_vector_type(4))) float f4v;   // MFMA accumulator

#define LOG2E 1.44269504088896340736f
// Finite "minus infinity": loses every fmax vs >= -1250 scaled scores; exp2
// of (mrun-mnew) underflows cleanly to 0.0 (no inf/NaN anywhere).
#define NEG_BIG (-30000.0f)

// Problem dims
#define BB 2
#define LL 2048
#define DD 1024
#define HH 16
#define HD 64
#define MTOT 4096      // B*L
#define PER_T 4194304  // B*H*L*HD elements per staged tensor (8 MiB bf16)

struct alignas(8) B4 { bf16 v[4]; };

// ---------------------------------------------------------------------------
// f32 -> bf16 bulk conversion. blockIdx.y selects the tensor (3 activations,
// 4 weight matrices). float4 loads, 8-byte bf16x4 stores, grid-stride.
// ---------------------------------------------------------------------------
struct CvtArgs {
    const float* src[7];
    bf16* dst[7];
    int n[7];
};

__global__ __launch_bounds__(256) void cvt_kernel(CvtArgs args) {
    const int which = blockIdx.y;
    const float* __restrict__ src = args.src[which];
    bf16* __restrict__ dst = args.dst[which];
    const int n4 = args.n[which] >> 2;
    const int stride = gridDim.x * 256;
    for (int i = blockIdx.x * 256 + threadIdx.x; i < n4; i += stride) {
        const float4 f = ((const float4*)src)[i];
        B4 o;
        o.v[0] = __float2bfloat16(f.x);
        o.v[1] = __float2bfloat16(f.y);
        o.v[2] = __float2bfloat16(f.z);
        o.v[3] = __float2bfloat16(f.w);
        ((B4*)dst)[i] = o;
    }
}

// ---------------------------------------------------------------------------
// C[m,n] = A[m,:] . W[n,:] + bias[n]   (m in [0,4096), n,k in [0,1024))
// A, W are bf16 (pre-converted); bias is f32.
// MODE 0: store head-major bf16  out[((b*16+h)*2048 + l)*64 + hd]   (Q, K)
// MODE 1: store head-major transposed bf16 out[((b*16+h)*64+hd)*2048+l] (V)
// MODE 2: plain [m,n] f32 store to d_out, gated by any(mask[b,:]).
// Per-wave tile 32x64 (acc[2][4]); block = 4 waves in 2x2 -> 64x128 tile.
// Grid: (4096/64, 1024/128) = (64, 8). Each block spans rows of a single b.
// ---------------------------------------------------------------------------
template <int MODE>
__global__ __launch_bounds__(256) void gemm_bt(const bf16* __restrict__ A,
                                               const bf16* __restrict__ W,
                                               const float* __restrict__ bias,
                                               bf16* __restrict__ out_bf,
                                               float* __restrict__ out_f,
                                               const int* __restrict__ mask) {
    __shared__ int sgate;
    const int lane = threadIdx.x & 63;
    const int w = threadIdx.x >> 6;
    const int lr = lane & 15;
    const int quad = lane >> 4;
    const int rbase = blockIdx.x * 64 + (w >> 1) * 32;
    const int cbase = blockIdx.y * 128 + (w & 1) * 64;
    const int koff = quad * 8;

    if (MODE == 2) {
        if (threadIdx.x == 0) sgate = 0;
        __syncthreads();
        const int b_ = (blockIdx.x * 64) >> 11;   // whole block is one batch
        int any = 0;
        for (int i = threadIdx.x; i < LL; i += 256) any |= mask[b_ * LL + i];
        if (any) sgate = 1;   // benign same-value race
        __syncthreads();
    }

    f4v acc[2][4] = {};
    for (int k0 = 0; k0 < DD; k0 += 32) {
        s8v a[2], b[4];
#pragma unroll
        for (int i = 0; i < 2; i++)
            a[i] = *(const s8v*)(A + (size_t)(rbase + i * 16 + lr) * DD + k0 + koff);
#pragma unroll
        for (int j = 0; j < 4; j++)
            b[j] = *(const s8v*)(W + (size_t)(cbase + j * 16 + lr) * DD + k0 + koff);
#pragma unroll
        for (int i = 0; i < 2; i++)
#pragma unroll
            for (int j = 0; j < 4; j++)
                acc[i][j] = __builtin_amdgcn_mfma_f32_16x16x32_bf16(a[i], b[j], acc[i][j], 0, 0, 0);
    }

    const float gatef = (MODE == 2) ? (sgate ? 1.0f : 0.0f) : 1.0f;

#pragma unroll
    for (int j = 0; j < 4; j++) {
        const int n = cbase + j * 16 + lr;
        const float bv = bias[n];
#pragma unroll
        for (int i = 0; i < 2; i++) {
#pragma unroll
            for (int r = 0; r < 4; r++) {
                const int m = rbase + i * 16 + quad * 4 + r;
                const float v = acc[i][j][r] + bv;
                if (MODE == 2) {
                    out_f[(size_t)m * DD + n] = v * gatef;
                } else {
                    const int b_ = m >> 11, l = m & (LL - 1);
                    const int h = n >> 6, hd = n & 63;
                    if (MODE == 0)
                        out_bf[(((size_t)(b_ * HH + h)) * LL + l) * HD + hd] = __float2bfloat16(v);
                    else
                        out_bf[(((size_t)(b_ * HH + h)) * HD + hd) * LL + l] = __float2bfloat16(v);
                }
            }
        }
    }
}

// ---------------------------------------------------------------------------
// Flash attention. One block per (b, h, q-block of 64). 4 waves, each wave
// owns 16 queries. K-tile loop of 64 keys: QK^T (MFMA), online softmax
// (in-register quad reductions), P->LDS (double-buffered)->A-layout, PV.
// Q,K: [B,H,L,HD] bf16; Vt: [B,H,HD,L] bf16; Aout: [B,L,D] bf16.
// ---------------------------------------------------------------------------
__global__ __launch_bounds__(256) void attn_kernel(const bf16* __restrict__ Q,
                                                   const bf16* __restrict__ K,
                                                   const bf16* __restrict__ Vt,
                                                   const int* __restrict__ mask,
                                                   bf16* __restrict__ Aout) {
    // double-buffered per-wave P scratch; stride 72 keeps 16B align per row
    __shared__ bf16 sP[2][4][16 * 72];

    const int lane = threadIdx.x & 63;
    const int w = threadIdx.x >> 6;
    const int lr = lane & 15;
    const int quad = lane >> 4;

    const int bid = blockIdx.x;       // b*512 + h*32 + qb
    const int qb = bid & 31;
    const int h = (bid >> 5) & 15;
    const int b = bid >> 9;

    const size_t head_off = ((size_t)(b * HH + h)) * LL * HD;
    const bf16* Qh = Q + head_off;
    const bf16* Kh = K + head_off;
    const bf16* Vh = Vt + head_off;   // [HD, L] per head
    const int q0 = qb * 64 + w * 16;

    // Q fragments (A-layout), resident for whole kernel
    const s8v aq0 = *(const s8v*)(Qh + (size_t)(q0 + lr) * HD + quad * 8);
    const s8v aq1 = *(const s8v*)(Qh + (size_t)(q0 + lr) * HD + 32 + quad * 8);

    f4v O[4] = {};        // 16q x 64d accumulator, C-layout per 16x16 d-tile
    float mrun[4], lrun[4];
#pragma unroll
    for (int r = 0; r < 4; r++) { mrun[r] = NEG_BIG; lrun[r] = 0.0f; }

    const int* mb = mask + b * LL;

    for (int kt = 0; kt < LL / 64; kt++) {
        const int kbase = kt * 64;
        bf16* sPw = &sP[kt & 1][w][0];

        // --- S = Q K^T for 16q x 64k ---
        f4v S[4] = {};
#pragma unroll
        for (int j = 0; j < 4; j++) {
            const bf16* kr = Kh + (size_t)(kbase + j * 16 + lr) * HD;
            const s8v b0 = *(const s8v*)(kr + quad * 8);
            const s8v b1 = *(const s8v*)(kr + 32 + quad * 8);
            S[j] = __builtin_amdgcn_mfma_f32_16x16x32_bf16(aq0, b0, S[j], 0, 0, 0);
            S[j] = __builtin_amdgcn_mfma_f32_16x16x32_bf16(aq1, b1, S[j], 0, 0, 0);
        }

        // --- scale + mask (mask fill is exactly -10000, unscaled) ---
        float sc[4][4];
#pragma unroll
        for (int j = 0; j < 4; j++) {
            const int valid = mb[kbase + j * 16 + lr];
#pragma unroll
            for (int r = 0; r < 4; r++)
                sc[j][r] = valid ? S[j][r] * 0.125f : -10000.0f;
        }

        // --- online softmax: row max, rescale, exp, row sum ---
        float alpha[4];
#pragma unroll
        for (int r = 0; r < 4; r++) {
            float v = fmaxf(fmaxf(sc[0][r], sc[1][r]), fmaxf(sc[2][r], sc[3][r]));
            v = fmaxf(v, __shfl_xor(v, 1));
            v = fmaxf(v, __shfl_xor(v, 2));
            v = fmaxf(v, __shfl_xor(v, 4));
            v = fmaxf(v, __shfl_xor(v, 8));
            const float mnew = fmaxf(mrun[r], v);
            alpha[r] = exp2f((mrun[r] - mnew) * LOG2E);   // finite, underflows to 0
            mrun[r] = mnew;
        }
#pragma unroll
        for (int r = 0; r < 4; r++) {
            float rs = 0.0f;
#pragma unroll
            for (int j = 0; j < 4; j++) {
                const float p = exp2f((sc[j][r] - mrun[r]) * LOG2E);  // (0,1]
                sc[j][r] = p;
                rs += p;
            }
            rs += __shfl_xor(rs, 1);
            rs += __shfl_xor(rs, 2);
            rs += __shfl_xor(rs, 4);
            rs += __shfl_xor(rs, 8);
            lrun[r] = lrun[r] * alpha[r] + rs;   // >= 1 after tile 0
            O[0][r] *= alpha[r];
            O[1][r] *= alpha[r];
            O[2][r] *= alpha[r];
            O[3][r] *= alpha[r];
        }

        // --- P: C-layout -> LDS [16 x 64], stride 72 ---
#pragma unroll
        for (int j = 0; j < 4; j++)
#pragma unroll
            for (int r = 0; r < 4; r++)
                sPw[(quad * 4 + r) * 72 + j * 16 + lr] = __float2bfloat16(sc[j][r]);

        // Cross-lane visibility for the P round-trip. Double-buffered sP
        // removes the WAR hazard across iterations; one barrier suffices.
        __syncthreads();

        // --- PV: A = P (from LDS), B = V^T fragments (16B contiguous) ---
        const s8v pa0 = *(const s8v*)(sPw + lr * 72 + quad * 8);
        const s8v pa1 = *(const s8v*)(sPw + lr * 72 + 32 + quad * 8);
#pragma unroll
        for (int dt = 0; dt < 4; dt++) {
            const bf16* vr = Vh + (size_t)(dt * 16 + lr) * LL + kbase;
            const s8v v0 = *(const s8v*)(vr + quad * 8);
            const s8v v1 = *(const s8v*)(vr + 32 + quad * 8);
            O[dt] = __builtin_amdgcn_mfma_f32_16x16x32_bf16(pa0, v0, O[dt], 0, 0, 0);
            O[dt] = __builtin_amdgcn_mfma_f32_16x16x32_bf16(pa1, v1, O[dt], 0, 0, 0);
        }
    }

    // --- epilogue: O / l, store to [B, L, D] bf16 ---
    float inv[4];
#pragma unroll
    for (int r = 0; r < 4; r++) inv[r] = 1.0f / lrun[r];
#pragma unroll
    for (int dt = 0; dt < 4; dt++) {
#pragma unroll
        for (int r = 0; r < 4; r++) {
            const int q = q0 + quad * 4 + r;
            const int dcol = h * HD + dt * 16 + lr;
            Aout[((size_t)(b * LL + q)) * DD + dcol] = __float2bfloat16(O[dt][r] * inv[r]);
        }
    }
}

// ---------------------------------------------------------------------------
extern "C" void kernel_launch(void* const* d_in, const int* in_sizes, int n_in,
                              void* d_out, int out_size, void* d_ws, size_t ws_size,
                              hipStream_t stream) {
    // ALL tensors are float32 (per reference); mask is int32.
    const float* query = (const float*)d_in[0];
    const float* key   = (const float*)d_in[1];
    const float* value = (const float*)d_in[2];
    const float* Wq = (const float*)d_in[3];
    const float* bq = (const float*)d_in[4];
    const float* Wk = (const float*)d_in[5];
    const float* bk = (const float*)d_in[6];
    const float* Wv = (const float*)d_in[7];
    const float* bv = (const float*)d_in[8];
    const float* Wo = (const float*)d_in[9];
    const float* bo = (const float*)d_in[10];
    const int* mask = (const int*)d_in[11];

    fprintf(stderr, "[kernel_launch] f32 path: ws=%zu out=%d mask_n=%d\n",
            ws_size, out_size, in_sizes[11]);

    // ws layout (bf16 elements):
    // [0)      qx,kx,vx   : converted activations, 3 x 4M
    // [12M)    wq,wk,wv,wo: converted weights, 4 x 1M
    // [16M)    Qs,Ks,Vst  : staged head-major Q,K and transposed V, 3 x 4M
    // [28M)    aws        : attention output [B,L,D], 4M     (total 64 MiB)
    bf16* base = (bf16*)d_ws;
    bf16* qx = base;
    bf16* kx = qx + PER_T;
    bf16* vx = kx + PER_T;
    bf16* wq = vx + PER_T;
    bf16* wk = wq + DD * DD;
    bf16* wv = wk + DD * DD;
    bf16* wo = wv + DD * DD;
    bf16* Qs = wo + DD * DD;
    bf16* Ks = Qs + PER_T;
    bf16* Vst = Ks + PER_T;
    bf16* aws = Vst + PER_T;

    CvtArgs ca;
    ca.src[0] = query; ca.dst[0] = qx; ca.n[0] = PER_T;
    ca.src[1] = key;   ca.dst[1] = kx; ca.n[1] = PER_T;
    ca.src[2] = value; ca.dst[2] = vx; ca.n[2] = PER_T;
    ca.src[3] = Wq;    ca.dst[3] = wq; ca.n[3] = DD * DD;
    ca.src[4] = Wk;    ca.dst[4] = wk; ca.n[4] = DD * DD;
    ca.src[5] = Wv;    ca.dst[5] = wv; ca.n[5] = DD * DD;
    ca.src[6] = Wo;    ca.dst[6] = wo; ca.n[6] = DD * DD;
    cvt_kernel<<<dim3(1024, 7), 256, 0, stream>>>(ca);

    dim3 g(MTOT / 64, DD / 128), blk(256);
    gemm_bt<0><<<g, blk, 0, stream>>>(qx, wq, bq, Qs, nullptr, nullptr);
    gemm_bt<0><<<g, blk, 0, stream>>>(kx, wk, bk, Ks, nullptr, nullptr);
    gemm_bt<1><<<g, blk, 0, stream>>>(vx, wv, bv, Vst, nullptr, nullptr);

    attn_kernel<<<BB * HH * (LL / 64), 256, 0, stream>>>(Qs, Ks, Vst, mask, aws);

    gemm_bt<2><<<g, blk, 0, stream>>>(aws, wo, bo, nullptr, (float*)d_out, mask);
}

// Round 6
// 487.524 us; speedup vs baseline: 1.1159x; 1.1159x over previous
//
#include <hip/hip_runtime.h>
#include <hip/hip_bf16.h>

typedef __hip_bfloat16 bf16;
typedef __attribute__((ext_vector_type(8))) short s8v;   // 8 x bf16 (4 VGPRs)
typedef __attribute__((ext_vector_type(4))) float f4v;   // MFMA accumulator

#define LOG2E 1.44269504088896340736f
#define NEG_BIG (-30000.0f)

#define BB 2
#define LL 2048
#define DD 1024
#define HH 16
#define HD 64
#define MTOT 4096
#define PER_T 4194304  // B*H*L*HD elements (8 MiB bf16)

struct alignas(8) B4 { bf16 v[4]; };

// async global->LDS 16B: data lands at lds + lane*16 (wave-uniform lds base)
__device__ __forceinline__ void async_cp16(const bf16* g, bf16* l) {
    __builtin_amdgcn_global_load_lds(
        (const __attribute__((address_space(1))) void*)g,
        (__attribute__((address_space(3))) void*)l, 16, 0, 0);
}

// ---------------------------------------------------------------------------
// f32 -> bf16 bulk conversion (3 activations + 4 weights)
// ---------------------------------------------------------------------------
struct CvtArgs {
    const float* src[7];
    bf16* dst[7];
    int n[7];
};

__global__ __launch_bounds__(256) void cvt_kernel(CvtArgs args) {
    const int which = blockIdx.y;
    const float* __restrict__ src = args.src[which];
    bf16* __restrict__ dst = args.dst[which];
    const int n4 = args.n[which] >> 2;
    const int stride = gridDim.x * 256;
    for (int i = blockIdx.x * 256 + threadIdx.x; i < n4; i += stride) {
        const float4 f = ((const float4*)src)[i];
        B4 o;
        o.v[0] = __float2bfloat16(f.x);
        o.v[1] = __float2bfloat16(f.y);
        o.v[2] = __float2bfloat16(f.z);
        o.v[3] = __float2bfloat16(f.w);
        ((B4*)dst)[i] = o;
    }
}

// ---------------------------------------------------------------------------
// C[m,n] = A[m,:].W[n,:] + bias[n].  64x64 block tile, 4 waves in 2x2 (each
// 32x32, acc[2][2]), grid (64,16) = 1024 blocks -> 16 waves/CU. Next-k
// fragments prefetched into registers to hide L2 latency.
// MODE 0: head-major bf16 store (Q,K); MODE 1: head-major transposed (V);
// MODE 2: f32 [m,n] store gated by any(mask[b,:]).
// ---------------------------------------------------------------------------
template <int MODE>
__global__ __launch_bounds__(256) void gemm_bt(const bf16* __restrict__ A,
                                               const bf16* __restrict__ W,
                                               const float* __restrict__ bias,
                                               bf16* __restrict__ out_bf,
                                               float* __restrict__ out_f,
                                               const int* __restrict__ mask) {
    __shared__ int sgate;
    const int lane = threadIdx.x & 63;
    const int w = threadIdx.x >> 6;
    const int lr = lane & 15;
    const int quad = lane >> 4;
    const int rbase = blockIdx.x * 64 + (w >> 1) * 32;
    const int cbase = blockIdx.y * 64 + (w & 1) * 32;
    const int koff = quad * 8;

    if (MODE == 2) {
        if (threadIdx.x == 0) sgate = 0;
        __syncthreads();
        const int b_ = (blockIdx.x * 64) >> 11;
        int any = 0;
        for (int i = threadIdx.x; i < LL; i += 256) any |= mask[b_ * LL + i];
        if (any) sgate = 1;
        __syncthreads();
    }

    const bf16* Ar0 = A + (size_t)(rbase + lr) * DD + koff;
    const bf16* Ar1 = A + (size_t)(rbase + 16 + lr) * DD + koff;
    const bf16* Wr0 = W + (size_t)(cbase + lr) * DD + koff;
    const bf16* Wr1 = W + (size_t)(cbase + 16 + lr) * DD + koff;

    s8v a0 = *(const s8v*)Ar0;
    s8v a1 = *(const s8v*)Ar1;
    s8v b0 = *(const s8v*)Wr0;
    s8v b1 = *(const s8v*)Wr1;

    f4v acc[2][2] = {};
    for (int k0 = 32; k0 <= DD; k0 += 32) {
        s8v na0 = a0, na1 = a1, nb0 = b0, nb1 = b1;
        if (k0 < DD) {
            na0 = *(const s8v*)(Ar0 + k0);
            na1 = *(const s8v*)(Ar1 + k0);
            nb0 = *(const s8v*)(Wr0 + k0);
            nb1 = *(const s8v*)(Wr1 + k0);
        }
        acc[0][0] = __builtin_amdgcn_mfma_f32_16x16x32_bf16(a0, b0, acc[0][0], 0, 0, 0);
        acc[0][1] = __builtin_amdgcn_mfma_f32_16x16x32_bf16(a0, b1, acc[0][1], 0, 0, 0);
        acc[1][0] = __builtin_amdgcn_mfma_f32_16x16x32_bf16(a1, b0, acc[1][0], 0, 0, 0);
        acc[1][1] = __builtin_amdgcn_mfma_f32_16x16x32_bf16(a1, b1, acc[1][1], 0, 0, 0);
        a0 = na0; a1 = na1; b0 = nb0; b1 = nb1;
    }

    const float gatef = (MODE == 2) ? (sgate ? 1.0f : 0.0f) : 1.0f;

#pragma unroll
    for (int j = 0; j < 2; j++) {
        const int n = cbase + j * 16 + lr;
        const float bv = bias[n];
#pragma unroll
        for (int i = 0; i < 2; i++) {
#pragma unroll
            for (int r = 0; r < 4; r++) {
                const int m = rbase + i * 16 + quad * 4 + r;
                const float v = acc[i][j][r] + bv;
                if (MODE == 2) {
                    out_f[(size_t)m * DD + n] = v * gatef;
                } else {
                    const int b_ = m >> 11, l = m & (LL - 1);
                    const int h = n >> 6, hd = n & 63;
                    if (MODE == 0)
                        out_bf[(((size_t)(b_ * HH + h)) * LL + l) * HD + hd] = __float2bfloat16(v);
                    else
                        out_bf[(((size_t)(b_ * HH + h)) * HD + hd) * LL + l] = __float2bfloat16(v);
                }
            }
        }
    }
}

// ---------------------------------------------------------------------------
// Flash attention, S^T formulation. Block = (b, h, 64 q), 4 waves x 16 q.
// K-tile (64x64) staged in LDS via global_load_lds (double-buffered, XOR
// bank swizzle); V early-loaded to regs; softmax reductions mostly
// in-register (2+2 shuffles); P exchanged per-wave through LDS.
// ---------------------------------------------------------------------------
__global__ __launch_bounds__(256, 4) void attn_kernel(const bf16* __restrict__ Q,
                                                      const bf16* __restrict__ K,
                                                      const bf16* __restrict__ Vt,
                                                      const int* __restrict__ mask,
                                                      bf16* __restrict__ Aout) {
    __shared__ bf16 sK[2][64 * 64];    // 16 KB, double-buffered K tile
    __shared__ bf16 sP[4][16 * 72];    // 9 KB, per-wave P scratch
    __shared__ float sBias[LL];        // 8 KB, mask -> additive bias

    const int lane = threadIdx.x & 63;
    const int w = threadIdx.x >> 6;
    const int lr = lane & 15;
    const int quad = lane >> 4;

    const int bid = blockIdx.x;
    const int qb = bid & 31;
    const int h = (bid >> 5) & 15;
    const int b = bid >> 9;

    const size_t head_off = ((size_t)(b * HH + h)) * LL * HD;
    const bf16* Qh = Q + head_off;
    const bf16* Kh = K + head_off;
    const bf16* Vh = Vt + head_off;
    const int q0 = qb * 64 + w * 16;

    // DMA lane mapping for one 8-row (1KB) group: row-in-group = lane>>3,
    // fetched column chunk = (lane&7) ^ (lane>>3)  [XOR swizzle]
    const int dma_r = lane >> 3;
    const int dma_c = ((lane & 7) ^ dma_r) * 8;

    // prologue: bias fill + stage K tile 0
    {
        const int* mb = mask + b * LL;
        for (int i = threadIdx.x; i < LL; i += 256)
            sBias[i] = mb[i] ? 0.0f : -10000.0f;
#pragma unroll
        for (int t = 0; t < 2; t++) {
            const int row8 = w * 2 + t;
            async_cp16(Kh + (size_t)(row8 * 8 + dma_r) * HD + dma_c,
                       &sK[0][row8 * 512]);
        }
    }
    __syncthreads();   // drains vmcnt -> tile 0 staged

    const s8v aq0 = *(const s8v*)(Qh + (size_t)(q0 + lr) * HD + quad * 8);
    const s8v aq1 = *(const s8v*)(Qh + (size_t)(q0 + lr) * HD + 32 + quad * 8);

    bf16* sPw = &sP[w][0];
    f4v O[4] = {};
    float mrun = NEG_BIG, lrun = 0.0f;

    int asrc[4];
#pragma unroll
    for (int r = 0; r < 4; r++) asrc[r] = (lane & 48) | (quad * 4 + r);

    for (int kt = 0; kt < LL / 64; kt++) {
        const int kbase = kt * 64;
        const bf16* kbuf = &sK[kt & 1][0];

        // stage next K tile into the other buffer
        if (kt < LL / 64 - 1) {
#pragma unroll
            for (int t = 0; t < 2; t++) {
                const int row8 = w * 2 + t;
                async_cp16(Kh + (size_t)(kbase + 64 + row8 * 8 + dma_r) * HD + dma_c,
                           &sK[(kt + 1) & 1][row8 * 512]);
            }
        }

        // V early (consumed after softmax, ~400 cyc of latency hiding)
        s8v v0[4], v1[4];
#pragma unroll
        for (int dt = 0; dt < 4; dt++) {
            const bf16* vr = Vh + (size_t)(dt * 16 + lr) * LL + kbase;
            v0[dt] = *(const s8v*)(vr + quad * 8);
            v1[dt] = *(const s8v*)(vr + 32 + quad * 8);
        }

        // T = K Q^T  (S^T: row = key-local, col = q)
        f4v T[4] = {};
#pragma unroll
        for (int j = 0; j < 4; j++) {
            const int row = 16 * j + lr;
            const int sw = row & 7;
            const s8v kb0 = *(const s8v*)&kbuf[row * 64 + ((quad ^ sw) * 8)];
            const s8v kb1 = *(const s8v*)&kbuf[row * 64 + (((quad + 4) ^ sw) * 8)];
            T[j] = __builtin_amdgcn_mfma_f32_16x16x32_bf16(kb0, aq0, T[j], 0, 0, 0);
            T[j] = __builtin_amdgcn_mfma_f32_16x16x32_bf16(kb1, aq1, T[j], 0, 0, 0);
        }

        // scores = T*scale + bias; per-lane max over 16, 2-shuffle reduce
        float mloc = NEG_BIG;
#pragma unroll
        for (int j = 0; j < 4; j++) {
            const f4v bj = *(const f4v*)&sBias[kbase + j * 16 + quad * 4];
#pragma unroll
            for (int r = 0; r < 4; r++) {
                T[j][r] = T[j][r] * 0.125f + bj[r];
                mloc = fmaxf(mloc, T[j][r]);
            }
        }
        mloc = fmaxf(mloc, __shfl_xor(mloc, 16));
        mloc = fmaxf(mloc, __shfl_xor(mloc, 32));
        const float mnew = fmaxf(mrun, mloc);
        const float alphaq = exp2f((mrun - mnew) * LOG2E);
        mrun = mnew;

        float ls = 0.0f;
#pragma unroll
        for (int j = 0; j < 4; j++)
#pragma unroll
            for (int r = 0; r < 4; r++) {
                const float e = exp2f((T[j][r] - mnew) * LOG2E);
                T[j][r] = e;
                ls += e;
            }
        ls += __shfl_xor(ls, 16);
        ls += __shfl_xor(ls, 32);
        lrun = lrun * alphaq + ls;

        // broadcast alpha to O's row layout (q = quad*4+r)
        float aB[4];
#pragma unroll
        for (int r = 0; r < 4; r++) aB[r] = __shfl(alphaq, asrc[r]);
#pragma unroll
        for (int dt = 0; dt < 4; dt++)
#pragma unroll
            for (int r = 0; r < 4; r++) O[dt][r] *= aB[r];

        // P^T (C-layout) -> LDS rows q, contiguous k; per-wave exchange
        asm volatile("" ::: "memory");
#pragma unroll
        for (int j = 0; j < 4; j++) {
            B4 pk;
            pk.v[0] = __float2bfloat16(T[j][0]);
            pk.v[1] = __float2bfloat16(T[j][1]);
            pk.v[2] = __float2bfloat16(T[j][2]);
            pk.v[3] = __float2bfloat16(T[j][3]);
            *(B4*)&sPw[lr * 72 + j * 16 + quad * 4] = pk;
        }
        asm volatile("s_waitcnt lgkmcnt(0)" ::: "memory");
        const s8v pa0 = *(const s8v*)(sPw + lr * 72 + quad * 8);
        const s8v pa1 = *(const s8v*)(sPw + lr * 72 + 32 + quad * 8);

#pragma unroll
        for (int dt = 0; dt < 4; dt++) {
            O[dt] = __builtin_amdgcn_mfma_f32_16x16x32_bf16(pa0, v0[dt], O[dt], 0, 0, 0);
            O[dt] = __builtin_amdgcn_mfma_f32_16x16x32_bf16(pa1, v1[dt], O[dt], 0, 0, 0);
        }

        __syncthreads();   // K-tile buffer handoff (also drains next-tile DMA)
    }

    const float linv = 1.0f / lrun;
    float lB[4];
#pragma unroll
    for (int r = 0; r < 4; r++) lB[r] = __shfl(linv, asrc[r]);
#pragma unroll
    for (int dt = 0; dt < 4; dt++)
#pragma unroll
        for (int r = 0; r < 4; r++) {
            const int q = q0 + quad * 4 + r;
            Aout[((size_t)(b * LL + q)) * DD + h * HD + dt * 16 + lr] =
                __float2bfloat16(O[dt][r] * lB[r]);
        }
}

// ---------------------------------------------------------------------------
extern "C" void kernel_launch(void* const* d_in, const int* in_sizes, int n_in,
                              void* d_out, int out_size, void* d_ws, size_t ws_size,
                              hipStream_t stream) {
    const float* query = (const float*)d_in[0];
    const float* key   = (const float*)d_in[1];
    const float* value = (const float*)d_in[2];
    const float* Wq = (const float*)d_in[3];
    const float* bq = (const float*)d_in[4];
    const float* Wk = (const float*)d_in[5];
    const float* bk = (const float*)d_in[6];
    const float* Wv = (const float*)d_in[7];
    const float* bv = (const float*)d_in[8];
    const float* Wo = (const float*)d_in[9];
    const float* bo = (const float*)d_in[10];
    const int* mask = (const int*)d_in[11];

    bf16* base = (bf16*)d_ws;
    bf16* qx = base;
    bf16* kx = qx + PER_T;
    bf16* vx = kx + PER_T;
    bf16* wq = vx + PER_T;
    bf16* wk = wq + DD * DD;
    bf16* wv = wk + DD * DD;
    bf16* wo = wv + DD * DD;
    bf16* Qs = wo + DD * DD;
    bf16* Ks = Qs + PER_T;
    bf16* Vst = Ks + PER_T;
    bf16* aws = Vst + PER_T;

    CvtArgs ca;
    ca.src[0] = query; ca.dst[0] = qx; ca.n[0] = PER_T;
    ca.src[1] = key;   ca.dst[1] = kx; ca.n[1] = PER_T;
    ca.src[2] = value; ca.dst[2] = vx; ca.n[2] = PER_T;
    ca.src[3] = Wq;    ca.dst[3] = wq; ca.n[3] = DD * DD;
    ca.src[4] = Wk;    ca.dst[4] = wk; ca.n[4] = DD * DD;
    ca.src[5] = Wv;    ca.dst[5] = wv; ca.n[5] = DD * DD;
    ca.src[6] = Wo;    ca.dst[6] = wo; ca.n[6] = DD * DD;
    cvt_kernel<<<dim3(1024, 7), 256, 0, stream>>>(ca);

    dim3 g(MTOT / 64, DD / 64), blk(256);
    gemm_bt<0><<<g, blk, 0, stream>>>(qx, wq, bq, Qs, nullptr, nullptr);
    gemm_bt<0><<<g, blk, 0, stream>>>(kx, wk, bk, Ks, nullptr, nullptr);
    gemm_bt<1><<<g, blk, 0, stream>>>(vx, wv, bv, Vst, nullptr, nullptr);

    attn_kernel<<<BB * HH * (LL / 64), 256, 0, stream>>>(Qs, Ks, Vst, mask, aws);

    gemm_bt<2><<<g, blk, 0, stream>>>(aws, wo, bo, nullptr, (float*)d_out, mask);
}

// Round 7
// 293.612 us; speedup vs baseline: 1.8529x; 1.6604x over previous
//
#include <hip/hip_runtime.h>
#include <hip/hip_bf16.h>

typedef __hip_bfloat16 bf16;
typedef __attribute__((ext_vector_type(8))) short s8v;   // 8 x bf16 (4 VGPRs)
typedef __attribute__((ext_vector_type(4))) float f4v;   // MFMA accumulator

#define LOG2E 1.44269504088896340736f
#define CSCALE (0.125f * LOG2E)          // fold 1/sqrt(64) and log2e
#define MASK_B2 (-14426.950408889634f)   // -10000 * LOG2E (log2-domain bias)
#define NEG_BIG (-30000.0f)

#define BB 2
#define LL 2048
#define DD 1024
#define HH 16
#define HD 64
#define MTOT 4096
#define PER_T 4194304  // B*H*L*HD elements (8 MiB bf16)

struct alignas(8) B4 { bf16 v[4]; };

// async global->LDS 16B: data lands at lds_base + lane*16 (base wave-uniform)
__device__ __forceinline__ void async_cp16(const bf16* g, bf16* l) {
    __builtin_amdgcn_global_load_lds(
        (const __attribute__((address_space(1))) void*)g,
        (__attribute__((address_space(3))) void*)l, 16, 0, 0);
}

// ---------------------------------------------------------------------------
// f32 -> bf16 bulk conversion (3 activations + 4 weights)
// ---------------------------------------------------------------------------
struct CvtArgs {
    const float* src[7];
    bf16* dst[7];
    int n[7];
};

__global__ __launch_bounds__(256) void cvt_kernel(CvtArgs args) {
    const int which = blockIdx.y;
    const float* __restrict__ src = args.src[which];
    bf16* __restrict__ dst = args.dst[which];
    const int n4 = args.n[which] >> 2;
    const int stride = gridDim.x * 256;
    for (int i = blockIdx.x * 256 + threadIdx.x; i < n4; i += stride) {
        const float4 f = ((const float4*)src)[i];
        B4 o;
        o.v[0] = __float2bfloat16(f.x);
        o.v[1] = __float2bfloat16(f.y);
        o.v[2] = __float2bfloat16(f.z);
        o.v[3] = __float2bfloat16(f.w);
        ((B4*)dst)[i] = o;
    }
}

// ---------------------------------------------------------------------------
// m97-style GEMM: C[m,n] = A[m,:].W[n,:] + bias[n]; 128x128 tile, BK=64,
// single-buffered LDS (2-barrier K-loop), global_load_lds w16, XOR swizzle.
// 4 waves in 2x2, each 64x64 (acc[4][4]); 16 MFMA : 8 ds_read_b128 per k-step.
// FUSED=1: grid.z in 0..2 selects Q/K/V projection; Q,K stored head-major,
//          V stored head-major transposed. FUSED=0: O-projection, f32 store
//          to d_out gated by any(mask[b,:]).
// LDS tile layout: row-major 64 el rows; chunk c of row r lives at c^(r&7).
// ---------------------------------------------------------------------------
struct QkvArgs {
    const bf16* A[3];
    const bf16* W[3];
    const float* bias[3];
    bf16* out[3];
};

template <int FUSED>
__global__ __launch_bounds__(256) void gemm128(QkvArgs qa,
                                               const bf16* __restrict__ Ao,
                                               const bf16* __restrict__ Wo_,
                                               const float* __restrict__ bo_,
                                               float* __restrict__ out_f,
                                               const int* __restrict__ mask) {
    __shared__ bf16 sA[128 * 64];
    __shared__ bf16 sB[128 * 64];
    __shared__ int sgate;

    const int which = FUSED ? blockIdx.z : 0;
    const bf16* __restrict__ A = FUSED ? qa.A[which] : Ao;
    const bf16* __restrict__ W = FUSED ? qa.W[which] : Wo_;
    const float* __restrict__ bias = FUSED ? qa.bias[which] : bo_;
    bf16* __restrict__ out_bf = FUSED ? qa.out[which] : nullptr;

    const int lane = threadIdx.x & 63;
    const int w = threadIdx.x >> 6;
    const int lr = lane & 15;
    const int quad = lane >> 4;
    const int wr = w >> 1, wc = w & 1;
    const int rbase = blockIdx.x * 128;
    const int cbase = blockIdx.y * 128;
    const int dma_r = lane >> 3;                   // row within 8-row group
    const int dma_cc = ((lane & 7) ^ dma_r) * 8;   // swizzled source chunk

    if (!FUSED) {
        if (threadIdx.x == 0) sgate = 0;
        __syncthreads();
        const int b_ = rbase >> 11;
        int any = 0;
        for (int i = threadIdx.x; i < LL; i += 256) any |= mask[b_ * LL + i];
        if (any) sgate = 1;   // benign same-value race; barriers below publish
    }

    f4v acc[4][4] = {};
    for (int kt = 0; kt < DD / 64; kt++) {
        const int k0 = kt * 64;
        __syncthreads();   // all waves done reading previous tile
#pragma unroll
        for (int t = 0; t < 4; t++) {
            const int g = w * 4 + t;               // 8-row group 0..15
            async_cp16(A + (size_t)(rbase + g * 8 + dma_r) * DD + k0 + dma_cc,
                       &sA[g * 512]);
            async_cp16(W + (size_t)(cbase + g * 8 + dma_r) * DD + k0 + dma_cc,
                       &sB[g * 512]);
        }
        __syncthreads();   // implicit vmcnt(0) drain -> tile staged
#pragma unroll
        for (int s = 0; s < 2; s++) {
            s8v a[4], b[4];
#pragma unroll
            for (int i = 0; i < 4; i++) {
                const int row = wr * 64 + i * 16 + lr;
                a[i] = *(const s8v*)&sA[row * 64 + (((s * 4 + quad) ^ (row & 7)) * 8)];
            }
#pragma unroll
            for (int j = 0; j < 4; j++) {
                const int row = wc * 64 + j * 16 + lr;
                b[j] = *(const s8v*)&sB[row * 64 + (((s * 4 + quad) ^ (row & 7)) * 8)];
            }
#pragma unroll
            for (int i = 0; i < 4; i++)
#pragma unroll
                for (int j = 0; j < 4; j++)
                    acc[i][j] = __builtin_amdgcn_mfma_f32_16x16x32_bf16(a[i], b[j], acc[i][j], 0, 0, 0);
        }
    }

    const float gatef = (!FUSED) ? (sgate ? 1.0f : 0.0f) : 1.0f;

#pragma unroll
    for (int j = 0; j < 4; j++) {
        const int n = cbase + wc * 64 + j * 16 + lr;
        const float bv = bias[n];
#pragma unroll
        for (int i = 0; i < 4; i++) {
#pragma unroll
            for (int r = 0; r < 4; r++) {
                const int m = rbase + wr * 64 + i * 16 + quad * 4 + r;
                const float v = acc[i][j][r] + bv;
                if (!FUSED) {
                    out_f[(size_t)m * DD + n] = v * gatef;
                } else {
                    const int b_ = m >> 11, l = m & (LL - 1);
                    const int h = n >> 6, hd = n & 63;
                    if (which == 2)
                        out_bf[(((size_t)(b_ * HH + h)) * HD + hd) * LL + l] = __float2bfloat16(v);
                    else
                        out_bf[(((size_t)(b_ * HH + h)) * LL + l) * HD + hd] = __float2bfloat16(v);
                }
            }
        }
    }
}

// ---------------------------------------------------------------------------
// Flash attention, S^T form, log2-domain softmax. Block = (b,h,64q), 4 waves
// x 16q. K AND V tiles (64 keys) staged in LDS via DMA, double-buffered.
// Ballot-gated O rescale (running max rarely updates after early tiles).
// ---------------------------------------------------------------------------
__global__ __launch_bounds__(256) void attn_kernel(const bf16* __restrict__ Q,
                                                   const bf16* __restrict__ K,
                                                   const bf16* __restrict__ Vt,
                                                   const int* __restrict__ mask,
                                                   bf16* __restrict__ Aout) {
    __shared__ bf16 sK[2][64 * 64];    // 16 KB
    __shared__ bf16 sV[2][64 * 64];    // 16 KB
    __shared__ bf16 sP[4][16 * 72];    // 9 KB per-wave P scratch
    __shared__ float sBias[LL];        // 8 KB log2-domain additive bias

    const int lane = threadIdx.x & 63;
    const int w = threadIdx.x >> 6;
    const int lr = lane & 15;
    const int quad = lane >> 4;

    const int bid = blockIdx.x;
    const int qb = bid & 31;
    const int h = (bid >> 5) & 15;
    const int b = bid >> 9;

    const size_t head_off = ((size_t)(b * HH + h)) * LL * HD;
    const bf16* Qh = Q + head_off;
    const bf16* Kh = K + head_off;
    const bf16* Vh = Vt + head_off;    // [HD][LL] per head
    const int q0 = qb * 64 + w * 16;

    const int dma_r = lane >> 3;
    const int dma_cc = ((lane & 7) ^ dma_r) * 8;
    const int sw = lr & 7;

    // prologue: bias fill + stage tile 0 (K and V)
    {
        const int* mb = mask + b * LL;
        for (int i = threadIdx.x; i < LL; i += 256)
            sBias[i] = mb[i] ? 0.0f : MASK_B2;
#pragma unroll
        for (int t = 0; t < 2; t++) {
            const int g = w * 2 + t;
            async_cp16(Kh + (size_t)(g * 8 + dma_r) * HD + dma_cc, &sK[0][g * 512]);
            async_cp16(Vh + (size_t)(g * 8 + dma_r) * LL + dma_cc, &sV[0][g * 512]);
        }
    }
    __syncthreads();

    const s8v aq0 = *(const s8v*)(Qh + (size_t)(q0 + lr) * HD + quad * 8);
    const s8v aq1 = *(const s8v*)(Qh + (size_t)(q0 + lr) * HD + 32 + quad * 8);

    bf16* sPw = &sP[w][0];
    f4v O[4] = {};
    float mrun = NEG_BIG, lrun = 0.0f;

    int asrc[4];
#pragma unroll
    for (int r = 0; r < 4; r++) asrc[r] = (lane & 48) | (quad * 4 + r);

    for (int kt = 0; kt < LL / 64; kt++) {
        const int kbase = kt * 64;
        const bf16* kb = &sK[kt & 1][0];
        const bf16* vb = &sV[kt & 1][0];

        // stage next K+V tile into the other buffer
        if (kt < LL / 64 - 1) {
            const int nb = (kt + 1) & 1;
#pragma unroll
            for (int t = 0; t < 2; t++) {
                const int g = w * 2 + t;
                async_cp16(Kh + (size_t)(kbase + 64 + g * 8 + dma_r) * HD + dma_cc,
                           &sK[nb][g * 512]);
                async_cp16(Vh + (size_t)(g * 8 + dma_r) * LL + kbase + 64 + dma_cc,
                           &sV[nb][g * 512]);
            }
        }

        // T = K Q^T (row = key-local, col = q)
        f4v T[4];
#pragma unroll
        for (int j = 0; j < 4; j++) {
            const int row = 16 * j + lr;
            const s8v kb0 = *(const s8v*)&kb[row * 64 + ((quad ^ sw) * 8)];
            const s8v kb1 = *(const s8v*)&kb[row * 64 + (((quad + 4) ^ sw) * 8)];
            f4v t = {};
            t = __builtin_amdgcn_mfma_f32_16x16x32_bf16(kb0, aq0, t, 0, 0, 0);
            T[j] = __builtin_amdgcn_mfma_f32_16x16x32_bf16(kb1, aq1, t, 0, 0, 0);
        }

        // V fragments from LDS now; consumed after softmax (latency hidden)
        s8v v0[4], v1[4];
#pragma unroll
        for (int dt = 0; dt < 4; dt++) {
            const int vrow = dt * 16 + lr;
            v0[dt] = *(const s8v*)&vb[vrow * 64 + ((quad ^ sw) * 8)];
            v1[dt] = *(const s8v*)&vb[vrow * 64 + (((quad + 4) ^ sw) * 8)];
        }

        // scores (log2 domain) + per-lane max over 16, 2-shuffle reduce
        float mloc = NEG_BIG;
#pragma unroll
        for (int j = 0; j < 4; j++) {
            const f4v bj = *(const f4v*)&sBias[kbase + j * 16 + quad * 4];
#pragma unroll
            for (int r = 0; r < 4; r++) {
                T[j][r] = T[j][r] * CSCALE + bj[r];
                mloc = fmaxf(mloc, T[j][r]);
            }
        }
        mloc = fmaxf(mloc, __shfl_xor(mloc, 16));
        mloc = fmaxf(mloc, __shfl_xor(mloc, 32));

        // ballot-gated rescale: only when the running max actually moves
        if (__any(mloc > mrun)) {
            const float mnew = fmaxf(mrun, mloc);
            const float alphaq = exp2f(mrun - mnew);
            mrun = mnew;
            lrun *= alphaq;
            float aB[4];
#pragma unroll
            for (int r = 0; r < 4; r++) aB[r] = __shfl(alphaq, asrc[r]);
#pragma unroll
            for (int dt = 0; dt < 4; dt++)
#pragma unroll
                for (int r = 0; r < 4; r++) O[dt][r] *= aB[r];
        }

        float ls = 0.0f;
#pragma unroll
        for (int j = 0; j < 4; j++)
#pragma unroll
            for (int r = 0; r < 4; r++) {
                const float e = exp2f(T[j][r] - mrun);
                T[j][r] = e;
                ls += e;
            }
        ls += __shfl_xor(ls, 16);
        ls += __shfl_xor(ls, 32);
        lrun += ls;

        // P (q rows, k contiguous) via per-wave LDS exchange
        asm volatile("" ::: "memory");
#pragma unroll
        for (int j = 0; j < 4; j++) {
            B4 pk;
            pk.v[0] = __float2bfloat16(T[j][0]);
            pk.v[1] = __float2bfloat16(T[j][1]);
            pk.v[2] = __float2bfloat16(T[j][2]);
            pk.v[3] = __float2bfloat16(T[j][3]);
            *(B4*)&sPw[lr * 72 + j * 16 + quad * 4] = pk;
        }
        asm volatile("s_waitcnt lgkmcnt(0)" ::: "memory");
        const s8v pa0 = *(const s8v*)(sPw + lr * 72 + quad * 8);
        const s8v pa1 = *(const s8v*)(sPw + lr * 72 + 32 + quad * 8);

#pragma unroll
        for (int dt = 0; dt < 4; dt++) {
            O[dt] = __builtin_amdgcn_mfma_f32_16x16x32_bf16(pa0, v0[dt], O[dt], 0, 0, 0);
            O[dt] = __builtin_amdgcn_mfma_f32_16x16x32_bf16(pa1, v1[dt], O[dt], 0, 0, 0);
        }

        __syncthreads();   // buffer handoff (drains next-tile DMA)
    }

    const float linv = 1.0f / lrun;
    float lB[4];
#pragma unroll
    for (int r = 0; r < 4; r++) lB[r] = __shfl(linv, asrc[r]);
#pragma unroll
    for (int dt = 0; dt < 4; dt++)
#pragma unroll
        for (int r = 0; r < 4; r++) {
            const int q = q0 + quad * 4 + r;
            Aout[((size_t)(b * LL + q)) * DD + h * HD + dt * 16 + lr] =
                __float2bfloat16(O[dt][r] * lB[r]);
        }
}

// ---------------------------------------------------------------------------
extern "C" void kernel_launch(void* const* d_in, const int* in_sizes, int n_in,
                              void* d_out, int out_size, void* d_ws, size_t ws_size,
                              hipStream_t stream) {
    const float* query = (const float*)d_in[0];
    const float* key   = (const float*)d_in[1];
    const float* value = (const float*)d_in[2];
    const float* Wq = (const float*)d_in[3];
    const float* bq = (const float*)d_in[4];
    const float* Wk = (const float*)d_in[5];
    const float* bk = (const float*)d_in[6];
    const float* Wv = (const float*)d_in[7];
    const float* bv = (const float*)d_in[8];
    const float* Wo = (const float*)d_in[9];
    const float* bo = (const float*)d_in[10];
    const int* mask = (const int*)d_in[11];

    bf16* base = (bf16*)d_ws;
    bf16* qx = base;
    bf16* kx = qx + PER_T;
    bf16* vx = kx + PER_T;
    bf16* wq = vx + PER_T;
    bf16* wk = wq + DD * DD;
    bf16* wv = wk + DD * DD;
    bf16* wo = wv + DD * DD;
    bf16* Qs = wo + DD * DD;
    bf16* Ks = Qs + PER_T;
    bf16* Vst = Ks + PER_T;
    bf16* aws = Vst + PER_T;

    CvtArgs ca;
    ca.src[0] = query; ca.dst[0] = qx; ca.n[0] = PER_T;
    ca.src[1] = key;   ca.dst[1] = kx; ca.n[1] = PER_T;
    ca.src[2] = value; ca.dst[2] = vx; ca.n[2] = PER_T;
    ca.src[3] = Wq;    ca.dst[3] = wq; ca.n[3] = DD * DD;
    ca.src[4] = Wk;    ca.dst[4] = wk; ca.n[4] = DD * DD;
    ca.src[5] = Wv;    ca.dst[5] = wv; ca.n[5] = DD * DD;
    ca.src[6] = Wo;    ca.dst[6] = wo; ca.n[6] = DD * DD;
    cvt_kernel<<<dim3(1024, 7), 256, 0, stream>>>(ca);

    QkvArgs qa;
    qa.A[0] = qx; qa.W[0] = wq; qa.bias[0] = bq; qa.out[0] = Qs;
    qa.A[1] = kx; qa.W[1] = wk; qa.bias[1] = bk; qa.out[1] = Ks;
    qa.A[2] = vx; qa.W[2] = wv; qa.bias[2] = bv; qa.out[2] = Vst;

    // fused Q/K/V projections: 32 x 8 x 3 = 768 blocks (~3/CU)
    gemm128<1><<<dim3(MTOT / 128, DD / 128, 3), 256, 0, stream>>>(
        qa, nullptr, nullptr, nullptr, nullptr, nullptr);

    attn_kernel<<<BB * HH * (LL / 64), 256, 0, stream>>>(Qs, Ks, Vst, mask, aws);

    QkvArgs dummy{};
    gemm128<0><<<dim3(MTOT / 128, DD / 128, 1), 256, 0, stream>>>(
        dummy, aws, wo, bo, (float*)d_out, mask);
}